// Round 5
// baseline (11362.347 us; speedup 1.0000x reference)
//
#include <hip/hip_runtime.h>
#include <hip/hip_bf16.h>
#include <stdint.h>

// ESN sizes (fixed by the reference)
#define NRR     4096
#define NBATCH  16
#define NFEAT   12
#define SEQLEN  1024
#define ALPHA_C 0.6f

typedef _Float16 f16x8 __attribute__((ext_vector_type(8)));
typedef _Float16 f16x2 __attribute__((ext_vector_type(2)));
typedef float    f32x4 __attribute__((ext_vector_type(4)));
typedef unsigned long long u64;

constexpr int WGS    = 256;            // one WG per CU; 16 A-rows each
constexpr int TPB    = 512;            // 8 waves
constexpr int WAVES  = 8;
constexpr int KCHUNK = NRR / WAVES;    // 512 K per wave
constexpr int FRAGS  = KCHUNK / 32;    // 16 MFMAs per wave per step

#define SC_AGENT __HIP_MEMORY_SCOPE_AGENT

// Relaxed agent-scope (sc1, device-coherent) ops: meet at the L3 point of
// coherence, bypass the non-coherent per-XCD L2s, no fences -> no L2
// writeback/invalidate storms. Proven correct in rounds 3-4.
__device__ __forceinline__ unsigned ld_rlx(const unsigned* p) {
    return __hip_atomic_load(p, __ATOMIC_RELAXED, SC_AGENT);
}
__device__ __forceinline__ u64 ld_rlx64(const void* p) {
    return __hip_atomic_load((const u64*)p, __ATOMIC_RELAXED, SC_AGENT);
}
__device__ __forceinline__ void st_rlx(unsigned* p, unsigned v) {
    __hip_atomic_store(p, v, __ATOMIC_RELAXED, SC_AGENT);
}
__device__ __forceinline__ void st_rlx_f32(float* p, float v) {
    __hip_atomic_store(p, v, __ATOMIC_RELAXED, SC_AGENT);
}

// NO grid barrier. Producer->consumer dataflow sync:
//  - producer WG g, update wave q (0..3) stores its r-slice (sc1), drains
//    vmcnt(0) (stores committed at L3), then lane0 publishes quarter-tag
//    tags[g*4+q] = epoch. Monotonic u32 stores, no RMW anywhere.
//  - consumer wave w polls ONLY the 128 quarter-tags of the 32 producer WGs
//    covering its K-chunk [512w, 512w+512): one u64 (2 tags) per lane.
//  - safety of the 2-deep r double-buffer is implied by the data dependency:
//    tag>=t+2 means that producer finished READING all of r_t, so when all
//    of a WG's producers reach t+2 nobody in its K-range still reads r_t's
//    buffer and the WG itself only overwrites its own slice after that.
__device__ __forceinline__ void wait_tags(const unsigned* tags, int wave,
                                          int lane, unsigned epoch) {
    const u64* tp = (const u64*)tags + 64 * wave + lane;
    for (;;) {
        u64 v = ld_rlx64(tp);
        bool ok = ((unsigned)v >= epoch) & ((unsigned)(v >> 32) >= epoch);
        if (__all(ok)) break;
        __builtin_amdgcn_s_sleep(2);
    }
}

__global__ __launch_bounds__(TPB, 1) void esn_persistent(
    const float* __restrict__ x,    // (16, 1024, 12)
    const float* __restrict__ r0,   // (1, 16, 4096)
    const float* __restrict__ A,    // (4096, 4096) row-major
    const float* __restrict__ Bm,   // (4096, 12)
    const float* __restrict__ bias, // (4096,)
    const float* __restrict__ Cw,   // (8, 4096)
    float* __restrict__ out,        // (16, 8)
    unsigned* __restrict__ tags,    // 256 WGs x 4 quarter-tags
    _Float16* __restrict__ rb0,     // (16, 4096) fp16 state, double buffer A
    _Float16* __restrict__ rb1,     // buffer B
    float* __restrict__ rfin)       // (16, 4096) fp32 final state
{
    const int wg    = blockIdx.x;
    const int tid   = threadIdx.x;
    const int wave  = tid >> 6;
    const int lane  = tid & 63;
    const int l15   = lane & 15;   // A-frag row-in-tile / B-frag batch col
    const int g     = lane >> 4;   // k-group 0..3
    const int nbase = wg * 16;

    __shared__ float lds_red[2][WAVES][16][16];  // double-buffered partials
    __shared__ float lds_x[2][NBATCH][NFEAT];
    __shared__ float lds_Bp[16][NFEAT];
    __shared__ float lds_bias[16];
    __shared__ float lds_out[4][128];

    // ---- A slice -> fp16 register fragments (A read exactly once) ----
    uint4 afrag[FRAGS];
    {
        const float* arow = A + (size_t)(nbase + l15) * NRR + wave * KCHUNK + g * 8;
#pragma unroll
        for (int i = 0; i < FRAGS; ++i) {
            const float4* p = (const float4*)(arow + i * 32);
            float4 f0 = p[0];
            float4 f1 = p[1];
            f16x8 h;
            h[0] = (_Float16)f0.x; h[1] = (_Float16)f0.y;
            h[2] = (_Float16)f0.z; h[3] = (_Float16)f0.w;
            h[4] = (_Float16)f1.x; h[5] = (_Float16)f1.y;
            h[6] = (_Float16)f1.z; h[7] = (_Float16)f1.w;
            afrag[i] = __builtin_bit_cast(uint4, h);
        }
    }

    // x prefetch mapping (tid<192): thread owns (batch xb, feat xf)
    const int xb = tid / NFEAT;
    const int xf = tid % NFEAT;
    const size_t xofs = (size_t)xb * SEQLEN * NFEAT + xf;

    if (tid < 16 * NFEAT)
        lds_Bp[xb][xf] = Bm[(size_t)(nbase + xb) * NFEAT + xf];
    if (tid < 16)
        lds_bias[tid] = bias[nbase + tid];
    if (tid < NBATCH * NFEAT)
        lds_x[0][xb][xf] = x[xofs];  // x[:, 0, :]

    // ---- master fp32 state: update thread tid<256 owns (batch=tid>>4, n=tid&15)
    //      update wave q (= wave, q<4) owns batches [4q, 4q+4) ----
    const int ub = tid >> 4;
    const int un = tid & 15;
    float rm = 0.0f;
    if (tid < 256) {
        rm = r0[ub * NRR + nbase + un];
        float hi = __shfl_down(rm, 1);
        if (!(un & 1)) {
            f16x2 h2; h2[0] = (_Float16)rm; h2[1] = (_Float16)hi;
            st_rlx((unsigned*)(rb0 + (size_t)ub * NRR + nbase + un),
                   __builtin_bit_cast(unsigned, h2));
        }
    }
    if (wave < 4) {
        asm volatile("s_waitcnt vmcnt(0)" ::: "memory");
        if (lane == 0) st_rlx(&tags[wg * 4 + wave], 1u);  // r_0 published
    }

    for (int t = 0; t < SEQLEN; ++t) {
        const _Float16* rcur = (t & 1) ? rb1 : rb0;
        _Float16*       rnxt = (t & 1) ? rb0 : rb1;

        // wait for the 32 producers covering this wave's K-chunk
        wait_tags(tags, wave, lane, (unsigned)(t + 1));

        // kick x[t+1] prefetch (plain cached load; L2 stays warm)
        float xp = 0.0f;
        if (tid < NBATCH * NFEAT && t + 1 < SEQLEN)
            xp = x[xofs + (size_t)(t + 1) * NFEAT];

        // S[n,b] partials over this wave's K-chunk; r via sc1 (L3) loads
        f32x4 acc = {0.f, 0.f, 0.f, 0.f};
        const _Float16* rrow = rcur + l15 * NRR + wave * KCHUNK + g * 8;
#pragma unroll
        for (int i = 0; i < FRAGS; ++i) {
            u64 lo = ld_rlx64(rrow + i * 32);
            u64 hi = ld_rlx64(rrow + i * 32 + 4);
            uint4 u;
            u.x = (unsigned)lo; u.y = (unsigned)(lo >> 32);
            u.z = (unsigned)hi; u.w = (unsigned)(hi >> 32);
            acc = __builtin_amdgcn_mfma_f32_16x16x32_f16(
                __builtin_bit_cast(f16x8, afrag[i]),
                __builtin_bit_cast(f16x8, u), acc, 0, 0, 0);
        }
        // D layout: col=lane&15 (batch), row=(lane>>4)*4+j. Store transposed
        // [w][batch][row] as one contiguous f32x4 into buffer t&1.
        *(f32x4*)&lds_red[t & 1][wave][l15][g * 4] = acc;
        __syncthreads();  // the ONLY intra-WG barrier per step

        if (tid < 256) {
            float s = 0.f;
#pragma unroll
            for (int w = 0; w < WAVES; ++w) s += lds_red[t & 1][w][ub][un];
            float p = lds_bias[un];
            const float* xr = lds_x[t & 1][ub];
#pragma unroll
            for (int f = 0; f < NFEAT; ++f) p += lds_Bp[un][f] * xr[f];
            rm = (1.0f - ALPHA_C) * rm + ALPHA_C * tanhf(s + p);
            float hi = __shfl_down(rm, 1);
            if (!(un & 1)) {
                f16x2 h2; h2[0] = (_Float16)rm; h2[1] = (_Float16)hi;
                st_rlx((unsigned*)(rnxt + (size_t)ub * NRR + nbase + un),
                       __builtin_bit_cast(unsigned, h2));
            }
            if (t == SEQLEN - 1)
                st_rlx_f32(&rfin[(size_t)ub * NRR + nbase + un], rm);
        }
        // land x prefetch into the other LDS buffer
        if (tid < NBATCH * NFEAT && t + 1 < SEQLEN)
            lds_x[(t + 1) & 1][xb][xf] = xp;

        // publish this WG's quarter-slices: drain stores, then tag
        if (wave < 4) {
            asm volatile("s_waitcnt vmcnt(0)" ::: "memory");
            if (lane == 0) st_rlx(&tags[wg * 4 + wave], (unsigned)(t + 2));
        }
    }

    // ---- readout: out[b,o] = sum_k rfin[b,k] * Cw[o,k], by WG 0 ----
    if (wg == 0) {
        // wait until ALL WGs published their final state (epoch 1025)
        {
            const u64* tq = (const u64*)tags + tid;  // 512 threads x 2 tags
            for (;;) {
                u64 v = ld_rlx64(tq);
                bool ok = ((unsigned)v >= SEQLEN + 1u) &
                          ((unsigned)(v >> 32) >= SEQLEN + 1u);
                if (__all(ok) && __syncthreads_and(1)) { /* keep structure */ }
                if (ok) break;
                __builtin_amdgcn_s_sleep(2);
            }
            __syncthreads();
        }
        const int oi   = tid & 127;  // = b*8 + o
        const int part = tid >> 7;   // K-quarter
        const int b = oi >> 3, o = oi & 7;
        const float* rv = rfin + (size_t)b * NRR + part * (NRR / 4);
        const float* cv = Cw   + (size_t)o * NRR + part * (NRR / 4);
        float s = 0.f;
        for (int k = 0; k < NRR / 4; k += 2) {
            u64 u = ld_rlx64(rv + k);
            float ra = __builtin_bit_cast(float, (unsigned)u);
            float rb = __builtin_bit_cast(float, (unsigned)(u >> 32));
            s += ra * cv[k] + rb * cv[k + 1];
        }
        lds_out[part][oi] = s;
        __syncthreads();
        if (tid < 128)
            out[tid] = lds_out[0][tid] + lds_out[1][tid] + lds_out[2][tid] + lds_out[3][tid];
    }
}

extern "C" void kernel_launch(void* const* d_in, const int* in_sizes, int n_in,
                              void* d_out, int out_size, void* d_ws, size_t ws_size,
                              hipStream_t stream) {
    const float* x   = (const float*)d_in[0];
    const float* r0  = (const float*)d_in[1];
    const float* A   = (const float*)d_in[2];
    const float* Bm  = (const float*)d_in[3];
    const float* bv  = (const float*)d_in[4];
    const float* Cw  = (const float*)d_in[5];
    float*       out = (float*)d_out;

    char* ws = (char*)d_ws;
    unsigned*  tags = (unsigned*)ws;                                   // 4 KB (1024 u32)
    _Float16*  rb0  = (_Float16*)(ws + 8192);                          // 128 KB
    _Float16*  rb1  = (_Float16*)(ws + 8192 + NRR * NBATCH * 2);       // 128 KB
    float*     rfin = (float*)(ws + 8192 + 2 * (NRR * NBATCH * 2));    // 256 KB

    // tags must start at 0 every call (incl. graph replays)
    hipMemsetAsync(ws, 0, 8192, stream);

    void* args[] = {(void*)&x, (void*)&r0, (void*)&A, (void*)&Bm, (void*)&bv, (void*)&Cw,
                    (void*)&out, (void*)&tags, (void*)&rb0, (void*)&rb1, (void*)&rfin};
    hipError_t e = hipLaunchCooperativeKernel((const void*)esn_persistent,
                                              dim3(WGS), dim3(TPB), args, 0, stream);
    if (e != hipSuccess) {
        hipLaunchKernelGGL(esn_persistent, dim3(WGS), dim3(TPB), 0, stream,
                           x, r0, A, Bm, bv, Cw, out, tags, rb0, rb1, rfin);
    }
}

// Round 6
// 6157.306 us; speedup vs baseline: 1.8453x; 1.8453x over previous
//
#include <hip/hip_runtime.h>
#include <hip/hip_bf16.h>
#include <stdint.h>

// ESN sizes (fixed by the reference)
#define NRR     4096
#define NBATCH  16
#define NFEAT   12
#define SEQLEN  1024
#define ALPHA_C 0.6f

typedef _Float16 f16x8 __attribute__((ext_vector_type(8)));
typedef _Float16 f16x2 __attribute__((ext_vector_type(2)));
typedef float    f32x4 __attribute__((ext_vector_type(4)));
typedef unsigned long long u64;

constexpr int WGS    = 256;            // one WG per CU; 16 A-rows each
constexpr int TPB    = 512;            // 8 waves
constexpr int WAVES  = 8;
constexpr int KCHUNK = NRR / WAVES;    // 512 K per wave
constexpr int FRAGS  = KCHUNK / 32;    // 16 MFMAs per wave per step
constexpr int NFLAG  = 16;             // replicated release-flag lines
constexpr int SLOTE  = NBATCH * NRR;   // fp16 elems per r-slot (128 KB)

#define SC_AGENT __HIP_MEMORY_SCOPE_AGENT

__device__ __forceinline__ unsigned ld_rlx(const unsigned* p) {
    return __hip_atomic_load(p, __ATOMIC_RELAXED, SC_AGENT);
}
__device__ __forceinline__ u64 ld_rlx64(const void* p) {
    return __hip_atomic_load((const u64*)p, __ATOMIC_RELAXED, SC_AGENT);
}
__device__ __forceinline__ void st_rlx(unsigned* p, unsigned v) {
    __hip_atomic_store(p, v, __ATOMIC_RELAXED, SC_AGENT);
}
__device__ __forceinline__ void st_rlx_f32(float* p, float v) {
    __hip_atomic_store(p, v, __ATOMIC_RELAXED, SC_AGENT);
}

// Two-level fence-free grid barrier (round-4 design, proven fastest), plus:
//  - optional agent-acquire (L1+L2 invalidate) BEFORE the arrival store when
//    the r ring reuses addresses (use_inv). All INVs complete before ANY WG
//    is released, so post-release L2 fills are never invalidated mid-step.
//  - compiler fence on poll exit so plain r-loads can't be hoisted above the
//    release observation (HW is in-order per wave; this pins the compiler).
__device__ __forceinline__ void gridbar(unsigned* slots, unsigned* flags,
                                        unsigned epoch, int wg, int tid,
                                        int lane, int wave, int use_inv) {
    __syncthreads();
    if (tid == 0) {
        if (use_inv)
            (void)__hip_atomic_load(&slots[wg], __ATOMIC_ACQUIRE, SC_AGENT);
        st_rlx(&slots[wg], epoch);
    }
    if ((wg | wave) == 0) {
        const u64* sp = (const u64*)slots;
        const int i0 = lane * 2;
        for (;;) {
            u64 a = ld_rlx64(&sp[i0]);
            u64 b = ld_rlx64(&sp[i0 + 1]);
            bool ok = ((unsigned)a >= epoch) & ((unsigned)(a >> 32) >= epoch) &
                      ((unsigned)b >= epoch) & ((unsigned)(b >> 32) >= epoch);
            if (__all(ok)) break;
            __builtin_amdgcn_s_sleep(1);
        }
        if (lane < NFLAG) st_rlx(&flags[lane * 32], epoch);
    } else {
        const unsigned* f = &flags[(wg & (NFLAG - 1)) * 32];
        while (ld_rlx(f) < epoch) __builtin_amdgcn_s_sleep(1);
    }
    asm volatile("" ::: "memory");  // keep r-loads below the release poll
}

__global__ __launch_bounds__(TPB, 1) void esn_persistent(
    const float* __restrict__ x,    // (16, 1024, 12)
    const float* __restrict__ r0,   // (1, 16, 4096)
    const float* __restrict__ A,    // (4096, 4096) row-major
    const float* __restrict__ Bm,   // (4096, 12)
    const float* __restrict__ bias, // (4096,)
    const float* __restrict__ Cw,   // (8, 4096)
    float* __restrict__ out,        // (16, 8)
    unsigned* __restrict__ slots,   // 256 arrival slots
    unsigned* __restrict__ flags,   // 16 release flags, 128B apart
    _Float16* __restrict__ rbuf,    // r ring: 1025 streaming slots (or 2 + INV)
    float* __restrict__ rfin,       // (16, 4096) fp32 final state
    int use_inv)                    // 0 = streaming ring, 1 = 2-slot ring + INV
{
    const int wg    = blockIdx.x;
    const int tid   = threadIdx.x;
    const int wave  = tid >> 6;
    const int lane  = tid & 63;
    const int l15   = lane & 15;   // A-frag row-in-tile / B-frag batch col
    const int g     = lane >> 4;   // k-group 0..3
    const int nbase = wg * 16;

    __shared__ float lds_red[WAVES][16][16];  // [w][batch][row]
    __shared__ float lds_x[2][NBATCH][NFEAT];
    __shared__ float lds_Bp[16][NFEAT];
    __shared__ float lds_bias[16];
    __shared__ float lds_out[4][128];

    // ---- A slice -> fp16 register fragments (A read exactly once) ----
    uint4 afrag[FRAGS];
    {
        const float* arow = A + (size_t)(nbase + l15) * NRR + wave * KCHUNK + g * 8;
#pragma unroll
        for (int i = 0; i < FRAGS; ++i) {
            const float4* p = (const float4*)(arow + i * 32);
            float4 f0 = p[0];
            float4 f1 = p[1];
            f16x8 h;
            h[0] = (_Float16)f0.x; h[1] = (_Float16)f0.y;
            h[2] = (_Float16)f0.z; h[3] = (_Float16)f0.w;
            h[4] = (_Float16)f1.x; h[5] = (_Float16)f1.y;
            h[6] = (_Float16)f1.z; h[7] = (_Float16)f1.w;
            afrag[i] = __builtin_bit_cast(uint4, h);
        }
    }

    // x prefetch mapping (tid<192): thread owns (batch xb, feat xf)
    const int xb = tid / NFEAT;
    const int xf = tid % NFEAT;
    const size_t xofs = (size_t)xb * SEQLEN * NFEAT + xf;

    if (tid < 16 * NFEAT)
        lds_Bp[xb][xf] = Bm[(size_t)(nbase + xb) * NFEAT + xf];
    if (tid < 16)
        lds_bias[tid] = bias[nbase + tid];
    if (tid < NBATCH * NFEAT)
        lds_x[0][xb][xf] = x[xofs];  // x[:, 0, :]

    // ---- master fp32 state: update thread tid<256 owns (batch=tid>>4, n=tid&15) ----
    const int ub = tid >> 4;
    const int un = tid & 15;
    float rm = 0.0f;
    if (tid < 256) {
        rm = r0[ub * NRR + nbase + un];
        float hi = __shfl_down(rm, 1);
        if (!(un & 1)) {
            f16x2 h2; h2[0] = (_Float16)rm; h2[1] = (_Float16)hi;
            st_rlx((unsigned*)(rbuf + (size_t)ub * NRR + nbase + un),
                   __builtin_bit_cast(unsigned, h2));
        }
    }

    gridbar(slots, flags, 1u, wg, tid, lane, wave, use_inv);

    const size_t roff = (size_t)l15 * NRR + wave * KCHUNK + g * 8;

    for (int t = 0; t < SEQLEN; ++t) {
        // streaming: fresh slot every step -> plain cached loads are safe and
        // the 32 WGs sharing each XCD-L2 fetch each 128B line ONCE per step.
        const _Float16* rcur = rbuf + (size_t)(use_inv ? (t & 1) : t) * SLOTE;
        _Float16*       rnxt = rbuf + (size_t)(use_inv ? ((t + 1) & 1) : (t + 1)) * SLOTE;

        // kick x[t+1] prefetch
        float xp = 0.0f;
        if (tid < NBATCH * NFEAT && t + 1 < SEQLEN)
            xp = x[xofs + (size_t)(t + 1) * NFEAT];

        // S[n,b] partials over this wave's K-chunk; r via PLAIN cached uint4
        f32x4 acc = {0.f, 0.f, 0.f, 0.f};
        const _Float16* rrow = rcur + roff;
#pragma unroll
        for (int i = 0; i < FRAGS; ++i) {
            uint4 u = *(const uint4*)(rrow + i * 32);
            acc = __builtin_amdgcn_mfma_f32_16x16x32_f16(
                __builtin_bit_cast(f16x8, afrag[i]),
                __builtin_bit_cast(f16x8, u), acc, 0, 0, 0);
        }
        // D layout: col=lane&15 (batch), row=(lane>>4)*4+j. Transposed store
        // [w][batch][row] as one contiguous f32x4.
        *(f32x4*)&lds_red[wave][l15][g * 4] = acc;
        __syncthreads();

        if (tid < 256) {
            float s = 0.f;
#pragma unroll
            for (int w = 0; w < WAVES; ++w) s += lds_red[w][ub][un];
            float p = lds_bias[un];
            const float* xr = lds_x[t & 1][ub];
#pragma unroll
            for (int f = 0; f < NFEAT; ++f) p += lds_Bp[un][f] * xr[f];
            rm = (1.0f - ALPHA_C) * rm + ALPHA_C * tanhf(s + p);
            float hi = __shfl_down(rm, 1);
            if (!(un & 1)) {
                f16x2 h2; h2[0] = (_Float16)rm; h2[1] = (_Float16)hi;
                st_rlx((unsigned*)(rnxt + (size_t)ub * NRR + nbase + un),
                       __builtin_bit_cast(unsigned, h2));
            }
            if (t == SEQLEN - 1)
                st_rlx_f32(&rfin[(size_t)ub * NRR + nbase + un], rm);
        }
        // land x prefetch into the other LDS buffer
        if (tid < NBATCH * NFEAT && t + 1 < SEQLEN)
            lds_x[(t + 1) & 1][xb][xf] = xp;

        gridbar(slots, flags, (unsigned)(t + 2), wg, tid, lane, wave, use_inv);
    }

    // ---- readout: out[b,o] = sum_k rfin[b,k] * Cw[o,k], by WG 0 ----
    // Final gridbar (epoch 1025) guarantees all rfin sc1 stores are at L3.
    if (wg == 0) {
        const int oi   = tid & 127;  // = b*8 + o
        const int part = tid >> 7;   // K-quarter
        const int b = oi >> 3, o = oi & 7;
        const float* rv = rfin + (size_t)b * NRR + part * (NRR / 4);
        const float* cv = Cw   + (size_t)o * NRR + part * (NRR / 4);
        float s = 0.f;
        for (int k = 0; k < NRR / 4; k += 2) {
            u64 u = ld_rlx64(rv + k);
            float ra = __builtin_bit_cast(float, (unsigned)u);
            float rb = __builtin_bit_cast(float, (unsigned)(u >> 32));
            s += ra * cv[k] + rb * cv[k + 1];
        }
        lds_out[part][oi] = s;
        __syncthreads();
        if (tid < 128)
            out[tid] = lds_out[0][tid] + lds_out[1][tid] + lds_out[2][tid] + lds_out[3][tid];
    }
}

extern "C" void kernel_launch(void* const* d_in, const int* in_sizes, int n_in,
                              void* d_out, int out_size, void* d_ws, size_t ws_size,
                              hipStream_t stream) {
    const float* x   = (const float*)d_in[0];
    const float* r0  = (const float*)d_in[1];
    const float* A   = (const float*)d_in[2];
    const float* Bm  = (const float*)d_in[3];
    const float* bv  = (const float*)d_in[4];
    const float* Cw  = (const float*)d_in[5];
    float*       out = (float*)d_out;

    char* ws = (char*)d_ws;
    unsigned*  slots = (unsigned*)ws;                       // 1 KB (256 x u32)
    unsigned*  flags = (unsigned*)(ws + 1024);              // 2 KB (16 lines)
    float*     rfin  = (float*)(ws + 4096);                 // 256 KB
    _Float16*  rbuf  = (_Float16*)(ws + 4096 + 262144);     // r ring

    // Streaming ring needs (SEQLEN+1) slots of 128 KB = ~134.6 MB total ws.
    const size_t need_stream = 4096 + 262144 + (size_t)(SEQLEN + 1) * SLOTE * 2;
    int use_inv = (ws_size >= need_stream) ? 0 : 1;

    // slots/flags must start at 0 every call (incl. graph replays)
    hipMemsetAsync(ws, 0, 4096, stream);

    void* args[] = {(void*)&x, (void*)&r0, (void*)&A, (void*)&Bm, (void*)&bv, (void*)&Cw,
                    (void*)&out, (void*)&slots, (void*)&flags, (void*)&rbuf, (void*)&rfin,
                    (void*)&use_inv};
    hipError_t e = hipLaunchCooperativeKernel((const void*)esn_persistent,
                                              dim3(WGS), dim3(TPB), args, 0, stream);
    if (e != hipSuccess) {
        hipLaunchKernelGGL(esn_persistent, dim3(WGS), dim3(TPB), 0, stream,
                           x, r0, A, Bm, bv, Cw, out, slots, flags, rbuf, rfin, use_inv);
    }
}